// Round 9
// baseline (453.279 us; speedup 1.0000x reference)
//
#include <hip/hip_runtime.h>

// messages: [B=64, E=4096, D=128] f32 ; tgt: [B,E] int32 in [0,N=512)
// out: [B, N, D] f32 segment-sum.
// R9: algorithm inversion. Stream messages SEQUENTIALLY (perfect coalescing,
// 1KB per wave-instruction) and scatter-add into out with fire-and-forget
// global f32 atomics. Output zeroed by a memset node first.
constexpr int B = 64, E = 4096, N = 512, D = 128;
constexpr int THREADS = 256;
constexpr int NBLK = 2048;             // 8 blocks/CU; grid-stride

__global__ __launch_bounds__(THREADS)
void scatter_stream(const float4* __restrict__ msgs4,
                    const int* __restrict__ tgt,
                    float* __restrict__ out) {
    const size_t total4 = (size_t)B * E * (D / 4);      // 8.4M float4 elements
    const size_t stride = (size_t)NBLK * THREADS;
    size_t i = (size_t)blockIdx.x * THREADS + threadIdx.x;
    #pragma unroll 4
    for (; i < total4; i += stride) {
        const float4 v = msgs4[i];                      // sequential, 1KB/wave
        const int row = (int)(i >> 5);                  // global row in [0,B*E)
        const int b   = row >> 12;                      // E = 4096
        const int n   = tgt[row];                       // broadcast within half-wave
        const int col = ((int)i & 31) << 2;
        float* o = out + (((size_t)(b * N + n)) << 7) + col;
        atomicAdd(o + 0, v.x);                          // no return -> fire-and-forget
        atomicAdd(o + 1, v.y);
        atomicAdd(o + 2, v.z);
        atomicAdd(o + 3, v.w);
    }
}

extern "C" void kernel_launch(void* const* d_in, const int* in_sizes, int n_in,
                              void* d_out, int out_size, void* d_ws, size_t ws_size,
                              hipStream_t stream) {
    const float4* msgs4 = (const float4*)d_in[0];
    const int*    tgt   = (const int*)d_in[1];
    float* out = (float*)d_out;
    hipMemsetAsync(out, 0, (size_t)out_size * sizeof(float), stream);
    scatter_stream<<<NBLK, THREADS, 0, stream>>>(msgs4, tgt, out);
}

// Round 10
// 32.901 us; speedup vs baseline: 13.7770x; 13.7770x over previous
//
#include <hip/hip_runtime.h>

// messages: [B=64, E=4096, D=128] f32 ; tgt: [B,E] int32 in [0,N=512)
// out: [B, N, D] f32 segment-sum.
// Fused kernel (best variant, R7): block owns (batch b, 64 output rows).
// Single-pass LDS bucket binning (1 LDS atomic + 1 LDS write per match),
// then 8-deep-MLP gather with float2 row loads. No global atomics, no ws.
// R9's sequential-stream + global-atomic alternative measured 14x WORSE
// (453us, WRITE_SIZE 536MB from atomic line write-back) -- do not revisit.
constexpr int B = 64, E = 4096, N = 512, D = 128;
constexpr int QN = 64;                 // segs owned per block
constexpr int CAP = 32;                // bucket slots per seg (lambda=8)
constexpr int OVF = 256;               // overflow list capacity (~never hit)
constexpr int THREADS = 512;           // 8 waves
constexpr int EPT = E / THREADS;       // 8 targets scanned per thread
constexpr int NBLK = B * (N / QN);     // 512 blocks

__global__ __launch_bounds__(THREADS)
void fused_seg_sum(const float* __restrict__ msgs,
                   const int* __restrict__ tgt,
                   float* __restrict__ out) {
    __shared__ int cnt[QN];                   // per-seg cursors
    __shared__ unsigned short lst[QN * CAP];  // fixed-slot buckets (4 KiB)
    __shared__ int novf;
    __shared__ unsigned int ovf[OVF];         // (n<<12)|e overflow entries

    const int tid  = threadIdx.x;
    const int lane = tid & 63;
    const int w    = tid >> 6;            // wave 0..7
    const int b    = blockIdx.x >> 3;     // 8 blocks per batch
    const int n0   = (blockIdx.x & 7) * QN;

    if (tid < QN) cnt[tid] = 0;
    if (tid == THREADS - 1) novf = 0;
    __syncthreads();

    // ---- single-pass binning: 1 LDS atomic + 1 LDS write per match ----
    const int* tb = tgt + b * E;
    #pragma unroll
    for (int t = 0; t < EPT; ++t) {
        const int n = tb[t * THREADS + tid] - n0;       // coalesced idx read
        if ((unsigned)n < (unsigned)QN) {
            const int e = t * THREADS + tid;
            const int slot = atomicAdd(&cnt[n], 1);
            if (slot < CAP) lst[n * CAP + slot] = (unsigned short)e;
            else {                                       // ~never taken
                const int o = atomicAdd(&novf, 1);
                if (o < OVF) ovf[o] = ((unsigned)n << 12) | (unsigned)e;
            }
        }
    }
    __syncthreads();

    // ---- gather: wave w owns segs n0+w*8 .. +7 ----
    const float2* mb = reinterpret_cast<const float2*>(msgs) + (size_t)b * E * 64;
    float2* ob = reinterpret_cast<float2*>(out) + ((size_t)b * N + n0) * 64;
    const int no = novf;                  // wave-uniform (post-barrier)
    #pragma unroll
    for (int s = 0; s < 8; ++s) {
        const int n = w * 8 + s;
        const int k = min(cnt[n], CAP);
        float ax = 0.f, ay = 0.f;
        for (int i = 0; i < k; i += 8) {           // one iter for typical k<=8
            int ee[8]; float wt[8];
            #pragma unroll
            for (int j = 0; j < 8; ++j) {
                const bool v = (i + j < k);         // wave-uniform
                ee[j] = v ? (int)lst[n * CAP + i + j] : 0;   // LDS broadcast
                wt[j] = v ? 1.f : 0.f;
            }
            float2 vv[8];
            #pragma unroll
            for (int j = 0; j < 8; ++j)             // 8 independent 512B loads
                vv[j] = mb[(size_t)ee[j] * 64 + lane];
            #pragma unroll
            for (int j = 0; j < 8; ++j) { ax += wt[j] * vv[j].x; ay += wt[j] * vv[j].y; }
        }
        if (no) {                                   // overflow safety net (~never)
            for (int o = 0; o < no && o < OVF; ++o) {
                const unsigned v = ovf[o];
                if ((int)(v >> 12) == n) {
                    const float2 r = mb[(size_t)(v & 0xFFFu) * 64 + lane];
                    ax += r.x; ay += r.y;
                }
            }
        }
        float2 r; r.x = ax; r.y = ay;
        ob[(size_t)n * 64 + lane] = r;              // covers every output once
    }
}

extern "C" void kernel_launch(void* const* d_in, const int* in_sizes, int n_in,
                              void* d_out, int out_size, void* d_ws, size_t ws_size,
                              hipStream_t stream) {
    const float* msgs = (const float*)d_in[0];
    const int*   tgt  = (const int*)d_in[1];
    float* out = (float*)d_out;
    fused_seg_sum<<<NBLK, THREADS, 0, stream>>>(msgs, tgt, out);
}